// Round 8
// baseline (269.677 us; speedup 1.0000x reference)
//
#include <hip/hip_runtime.h>

#define B_    8
#define D_IN  256
#define D_HID 1024
#define D_OUT 40000       // = 200*200
#define HW4   10000       // D_OUT/4
#define CHW4  2560000     // 256*200*200/4
#define TOT4  20480000    // 8*CHW4
#define NBLK  512
#define NTHR  256

typedef float f32x4 __attribute__((ext_vector_type(4)));
typedef unsigned long long u64;

// ---- device-scope grid barrier (all NBLK blocks co-resident by construction) ----
__device__ __forceinline__ void grid_barrier(unsigned* cnt, unsigned* gen) {
    __syncthreads();   // per-wave vmcnt(0) drain before s_barrier: block's stores done
    if (threadIdx.x == 0) {
        unsigned g = __hip_atomic_load(gen, __ATOMIC_RELAXED, __HIP_MEMORY_SCOPE_AGENT);
        unsigned prev = __hip_atomic_fetch_add(cnt, 1u, __ATOMIC_ACQ_REL, __HIP_MEMORY_SCOPE_AGENT);
        if (prev == (unsigned)(NBLK - 1)) {
            // last arriver: reset counter, publish new generation (release orders reset first)
            __hip_atomic_store(cnt, 0u, __ATOMIC_RELAXED, __HIP_MEMORY_SCOPE_AGENT);
            __hip_atomic_store(gen, g + 1u, __ATOMIC_RELEASE, __HIP_MEMORY_SCOPE_AGENT);
        } else {
            while (__hip_atomic_load(gen, __ATOMIC_RELAXED, __HIP_MEMORY_SCOPE_AGENT) == g)
                __builtin_amdgcn_s_sleep(16);
            __builtin_amdgcn_fence(__ATOMIC_ACQUIRE, "agent");   // L1/L2 inv for this CU/XCD
        }
    }
    __syncthreads();
}

// agent-scope 16B store as 2x64-bit atomics: guaranteed visible at coherence point
__device__ __forceinline__ void store16_agent(f32x4 v, f32x4* p) {
    union { f32x4 v; u64 q[2]; } u;
    u.v = v;
    u64* d = (u64*)p;
    __hip_atomic_store(d,     u.q[0], __ATOMIC_RELAXED, __HIP_MEMORY_SCOPE_AGENT);
    __hip_atomic_store(d + 1, u.q[1], __ATOMIC_RELAXED, __HIP_MEMORY_SCOPE_AGENT);
}

template<int KS>
__global__ __launch_bounds__(NTHR, 4)     // VGPR<=128 -> >=4 blocks/CU capacity (2x margin)
void fused_kernel(const float* __restrict__ x,
                  const float* __restrict__ loc,
                  const float* __restrict__ W1,
                  const float* __restrict__ b1,
                  const float* __restrict__ W2,
                  const float* __restrict__ b2,
                  float* __restrict__ out,
                  unsigned* __restrict__ bar,     // cnt@0, gen@32, work@64 (words)
                  float* __restrict__ hT,
                  float* __restrict__ partial,
                  float* __restrict__ wmap) {
    unsigned* cnt  = bar;
    unsigned* gen  = bar + 32;      // separate cachelines
    unsigned* work = bar + 64;

    __shared__ float red[NTHR];
    const int bid  = blockIdx.x;
    const int tid  = threadIdx.x;
    const int wid  = tid >> 6;
    const int lane = tid & 63;

    // ---------- P1: hT = leakyrelu(loc @ W1 + b1), blocks 0..127 ----------
    if (bid < 128) {
        int b  = bid >> 4;
        int k0 = (bid & 15) * 64;
        int k  = k0 + lane;
        float acc = 0.0f;
        #pragma unroll 8
        for (int ii = 0; ii < 64; ++ii) {
            int i = wid * 64 + ii;
            acc += loc[b * D_IN + i] * W1[i * D_HID + k];
        }
        red[tid] = acc;
        __syncthreads();
        if (wid == 0) {
            float s = red[lane] + red[64 + lane] + red[128 + lane] + red[192 + lane];
            s += b1[k];
            s = (s >= 0.0f) ? s : 0.1f * s;
            __hip_atomic_store(&hT[k * B_ + b], s, __ATOMIC_RELAXED, __HIP_MEMORY_SCOPE_AGENT);
        }
    }
    grid_barrier(cnt, gen);

    // ---------- P2: split-K partial GEMM, work-stolen (jblk, ks) units ----------
    {
        constexpr int CHUNK  = D_HID / KS;
        constexpr unsigned NUNITS = 157u * KS;
        const f32x4* __restrict__ W24 = (const f32x4*)W2;
        f32x4* __restrict__ p4 = (f32x4*)partial;
        for (;;) {
            unsigned u;
            if (lane == 0)
                u = __hip_atomic_fetch_add(work, 1u, __ATOMIC_RELAXED, __HIP_MEMORY_SCOPE_AGENT);
            u = (unsigned)__shfl((int)u, 0);
            if (u >= NUNITS) break;
            int jblk = (int)(u % 157u);
            int ks   = (int)(u / 157u);
            int j4   = jblk * 64 + lane;
            if (j4 < HW4) {
                int k0 = ks * CHUNK;
                f32x4 acc[B_];
                #pragma unroll
                for (int b = 0; b < B_; ++b) acc[b] = (f32x4)0.0f;
                #pragma unroll 4
                for (int kk = 0; kk < CHUNK; ++kk) {
                    int k = k0 + kk;
                    f32x4 wv = __builtin_nontemporal_load(&W24[k * HW4 + j4]);
                    const float* __restrict__ h = &hT[k * B_];   // wave-uniform, L2-hit
                    #pragma unroll
                    for (int b = 0; b < B_; ++b)
                        acc[b] += wv * h[b];
                }
                #pragma unroll
                for (int b = 0; b < B_; ++b)
                    store16_agent(acc[b], &p4[(ks * B_ + b) * HW4 + j4]);
            }
        }
    }
    grid_barrier(cnt, gen);

    // ---------- P3: wmap = 1 + b2 + sum_ks partial ----------
    {
        int t = bid * NTHR + tid;          // 131072 threads >= 80000 items
        if (t < B_ * HW4) {
            int b  = t / HW4;
            int j4 = t - b * HW4;
            const f32x4* __restrict__ p4  = (const f32x4*)partial;
            const f32x4* __restrict__ b24 = (const f32x4*)b2;
            f32x4 s = b24[j4] + 1.0f;
            #pragma unroll
            for (int ks = 0; ks < KS; ++ks)
                s += p4[(ks * B_ + b) * HW4 + j4];
            store16_agent(s, &((f32x4*)wmap)[b * HW4 + j4]);
        }
    }
    grid_barrier(cnt, gen);

    // ---------- P4: out = x * wmap (grid-stride contiguous sweep) ----------
    {
        const f32x4* __restrict__ x4 = (const f32x4*)x;
        const f32x4* __restrict__ w4 = (const f32x4*)wmap;
        f32x4* __restrict__ o4 = (f32x4*)out;
        const int stride = NBLK * NTHR;
        #pragma unroll 4
        for (int i = bid * NTHR + tid; i < TOT4; i += stride) {
            unsigned int b = (unsigned int)i / CHW4;     // magic-mul
            unsigned int p = (unsigned int)i % HW4;      // CHW4 multiple of HW4
            f32x4 xv = __builtin_nontemporal_load(&x4[i]);
            f32x4 wv = w4[b * HW4 + p];                  // L2-cached after first touch
            __builtin_nontemporal_store(xv * wv, &o4[i]);
        }
    }
}

template<int KS>
static void launch_fused(const float* x, const float* loc, const float* W1,
                         const float* b1, const float* W2, const float* b2,
                         float* out, unsigned* bar, float* hT, float* partial,
                         float* wmap, hipStream_t stream) {
    fused_kernel<KS><<<NBLK, NTHR, 0, stream>>>(x, loc, W1, b1, W2, b2, out,
                                                bar, hT, partial, wmap);
}

extern "C" void kernel_launch(void* const* d_in, const int* in_sizes, int n_in,
                              void* d_out, int out_size, void* d_ws, size_t ws_size,
                              hipStream_t stream) {
    const float* x   = (const float*)d_in[0];
    const float* loc = (const float*)d_in[1];
    const float* W1  = (const float*)d_in[2];
    const float* b1  = (const float*)d_in[3];
    const float* W2  = (const float*)d_in[4];
    const float* b2  = (const float*)d_in[5];
    float* out = (float*)d_out;

    unsigned* bar  = (unsigned*)d_ws;                    // 512 B barrier/work state
    float* hT      = (float*)((char*)d_ws + 512);        // 32 KB
    float* partial = (float*)((char*)d_ws + 512 + 32768);

    size_t base = 512 + 32768;
    int KS = 1;
    for (int cand = 16; cand >= 1; cand >>= 1) {
        size_t need = base + (size_t)(cand + 1) * B_ * D_OUT * sizeof(float);
        if (need <= ws_size) { KS = cand; break; }
    }
    float* wmap = (float*)((char*)d_ws + base
                           + (size_t)KS * B_ * D_OUT * sizeof(float));

    // reset barrier generation/counters every call: deterministic, capture-safe
    hipMemsetAsync(d_ws, 0, 512, stream);

    switch (KS) {
        case 16: launch_fused<16>(x, loc, W1, b1, W2, b2, out, bar, hT, partial, wmap, stream); break;
        case 8:  launch_fused<8> (x, loc, W1, b1, W2, b2, out, bar, hT, partial, wmap, stream); break;
        case 4:  launch_fused<4> (x, loc, W1, b1, W2, b2, out, bar, hT, partial, wmap, stream); break;
        case 2:  launch_fused<2> (x, loc, W1, b1, W2, b2, out, bar, hT, partial, wmap, stream); break;
        default: launch_fused<1> (x, loc, W1, b1, W2, b2, out, bar, hT, partial, wmap, stream); break;
    }
}